// Round 1
// 1692.840 us; speedup vs baseline: 1.5919x; 1.5919x over previous
//
// Fused 2-layer GRU + classifier head, MI355X gfx950.
// B=2048, T=1024, D=64, H=32. Inputs/outputs FLOAT32; bf16 MFMA internally.
//
// Design (round 3):
//  - 128 blocks x 64 threads (1 wave). Each wave owns 16 batch rows, runs all
//    1024 timesteps for BOTH layers; h0/h1 live in registers. No LDS.
//  - SOFTWARE-PIPELINED LAYERS: iteration i computes L0(i) and L1(i-1)
//    concurrently. Both read h0f(i-1) (read-only), so all 30 MFMAs and both
//    gate-updates in an iteration are mutually independent -> per-step
//    critical path = max(layer chains), not their sum.
//  - x prefetch: 2-deep raw float4 queue (qA/qB), loads issued ~2 iterations
//    before use; bf16 conversion deferred to end of the iteration preceding
//    use, so s_waitcnt vmcnt sinks far from the issue point. Loop unrolled
//    by 2 so the queue rotates by renaming (no register copies forcing waits).
//  - bf16 packing via __float2bfloat16 pairs -> compiler emits
//    v_cvt_pk_bf16_f32 (1 instr / 2 elements) instead of 4-op RNE bit-twiddle.
//  - MFMA: D[gate][batch] = W' @ h^T (M=96 gates as 6 16-row tiles, N=16
//    batch, K=32/64), mfma_f32_16x16x32_bf16, fp32 accumulate.
//  - rho row-permutation rho(16*tau+4*q+r)=8q+4*tau+r: z/n tiles' C/D
//    registers land exactly in B-operand layout for the next step's hidden
//    matvec -> zero cross-lane movement per step.
//  - Pre-scaling: r,z rows * -log2(e) -> sigmoid = rcp(1+exp2(acc));
//                 n rows  * 2*log2(e) -> tanh    = 1-2*rcp(1+exp2(acc)).
//    fp32 biases folded into MFMA C-init fragments (free).

#include <hip/hip_runtime.h>
#include <hip/hip_bf16.h>

#define B_ 2048
#define T_ 1024

typedef short short8 __attribute__((ext_vector_type(8)));
typedef float floatx4 __attribute__((ext_vector_type(4)));

#define MFMA16(a, b, c) __builtin_amdgcn_mfma_f32_16x16x32_bf16((a), (b), (c), 0, 0, 0)
#define NLOG2E -1.4426950408889634f
#define TWOLOG2E 2.8853900817779268f

// init-time scalar fp32->bf16 RNE (weight fragments only)
__device__ __forceinline__ unsigned short f2bf(float f) {
  union { float f; unsigned int i; } v;
  v.f = f;
  unsigned int r = v.i + 0x7fffu + ((v.i >> 16) & 1u);  // RNE
  return (unsigned short)(r >> 16);
}

// hot-loop pack: compiler fuses the two scalar casts into v_cvt_pk_bf16_f32
__device__ __forceinline__ unsigned int pack2(float lo, float hi) {
  __hip_bfloat162 h2;
  h2.x = __float2bfloat16(lo);
  h2.y = __float2bfloat16(hi);
  union { __hip_bfloat162 h; unsigned int u; } v;
  v.h = h2;
  return v.u;
}

// position within a 32-row gate block -> logical (torch) row index
__device__ __forceinline__ int rho32(int pb) {
  return 8 * ((pb >> 2) & 3) + 4 * (pb >> 4) + (pb & 3);
}

// A-operand fragment of permuted+prescaled weight matrix W' (96 x K), fp32 src.
__device__ __forceinline__ short8 load_wfrag(const float* W, int K,
                                             int mt, int kt, int q, int c) {
  int p = 16 * mt + c;
  int blk = p >> 5;
  int pb = p & 31;
  int tr = 32 * blk + rho32(pb);
  float s = (blk < 2) ? NLOG2E : TWOLOG2E;
  const float* src = W + tr * K + 32 * kt + 8 * q;
  short8 out;
#pragma unroll
  for (int j = 0; j < 8; j++) out[j] = (short)f2bf(src[j] * s);
  return out;
}

// C-init fragment for r,z tiles (tau 0..3): -log2e*(b_ih+b_hh), permuted rows
__device__ __forceinline__ floatx4 bias_rz(const float* bih, const float* bhh,
                                           int tau, int q) {
  floatx4 f;
#pragma unroll
  for (int r = 0; r < 4; r++) {
    int p = 16 * tau + 4 * q + r;
    int idx = 32 * (p >> 5) + rho32(p & 31);
    f[r] = NLOG2E * (bih[idx] + bhh[idx]);
  }
  return f;
}
// C-init fragment for n tiles: 2*log2e * bias[64 + rho]
__device__ __forceinline__ floatx4 bias_n(const float* bias, int tau2, int q) {
  floatx4 f;
#pragma unroll
  for (int r = 0; r < 4; r++) {
    int pb = 16 * tau2 + 4 * q + r;
    f[r] = TWOLOG2E * bias[64 + rho32(pb)];
  }
  return f;
}

// raw (fp32) x for one step: lane(q,c) holds x[b][t][8q..8q+7] and [32+8q..+7]
struct XRaw { float4 r0, r1, r2, r3; };
__device__ __forceinline__ XRaw xload(const float* p) {
  XRaw r;
  r.r0 = *(const float4*)p;
  r.r1 = *(const float4*)(p + 4);
  r.r2 = *(const float4*)(p + 32);
  r.r3 = *(const float4*)(p + 36);
  return r;
}
__device__ __forceinline__ void xconv(const XRaw& r, short8& f0, short8& f1) {
  union { short8 s8; unsigned int u[4]; } P;
  P.u[0] = pack2(r.r0.x, r.r0.y);
  P.u[1] = pack2(r.r0.z, r.r0.w);
  P.u[2] = pack2(r.r1.x, r.r1.y);
  P.u[3] = pack2(r.r1.z, r.r1.w);
  f0 = P.s8;
  P.u[0] = pack2(r.r2.x, r.r2.y);
  P.u[1] = pack2(r.r2.z, r.r2.w);
  P.u[2] = pack2(r.r3.x, r.r3.y);
  P.u[3] = pack2(r.r3.z, r.r3.w);
  f1 = P.s8;
}

// GRU gate elementwise + h update + bf16 repack into B-operand fragment.
__device__ __forceinline__ void gru_update(const floatx4* arz, const floatx4* anx,
                                           const floatx4* anh, float* h,
                                           short8* hf) {
#pragma unroll
  for (int t2 = 0; t2 < 2; t2++) {
#pragma unroll
    for (int r = 0; r < 4; r++) {
      float rr = __builtin_amdgcn_rcpf(1.0f + __builtin_amdgcn_exp2f(arz[t2][r]));
      float zz = __builtin_amdgcn_rcpf(1.0f + __builtin_amdgcn_exp2f(arz[2 + t2][r]));
      float u = fmaf(rr, anh[t2][r], anx[t2][r]);
      float nn = fmaf(-2.0f, __builtin_amdgcn_rcpf(1.0f + __builtin_amdgcn_exp2f(u)), 1.0f);
      int j = 4 * t2 + r;
      h[j] = fmaf(zz, h[j] - nn, nn);  // (1-z)*n + z*h
    }
  }
  union { short8 s8; unsigned int u[4]; } P;
#pragma unroll
  for (int k2 = 0; k2 < 4; k2++) P.u[k2] = pack2(h[2 * k2], h[2 * k2 + 1]);
  *hf = P.s8;
}

// All 18 layer-0 MFMAs for one step (xa/xb = x frags, h0in = h0f fragment).
#define LAYER0_MFMAS(xa, xb, h0in)                              \
  {                                                             \
    _Pragma("unroll") for (int tau = 0; tau < 4; tau++) {       \
      floatx4 a_ = MFMA16(Aih0[tau][0], (xa), brz0[tau]);       \
      a_ = MFMA16(Aih0[tau][1], (xb), a_);                      \
      arz0[tau] = MFMA16(Ahh0[tau], (h0in), a_);                \
    }                                                           \
    _Pragma("unroll") for (int t2 = 0; t2 < 2; t2++) {          \
      floatx4 a_ = MFMA16(Aih0[4 + t2][0], (xa), bnx0[t2]);     \
      anx0[t2] = MFMA16(Aih0[4 + t2][1], (xb), a_);             \
      anh0[t2] = MFMA16(Ahh0[4 + t2], (h0in), bnh0[t2]);        \
    }                                                           \
  }

// All 12 layer-1 MFMAs for one step.
#define LAYER1_MFMAS(h0in, h1in)                                \
  {                                                             \
    _Pragma("unroll") for (int tau = 0; tau < 4; tau++) {       \
      floatx4 a_ = MFMA16(Aih1[tau], (h0in), brz1[tau]);        \
      arz1[tau] = MFMA16(Ahh1[tau], (h1in), a_);                \
    }                                                           \
    _Pragma("unroll") for (int t2 = 0; t2 < 2; t2++) {          \
      anx1[t2] = MFMA16(Aih1[4 + t2], (h0in), bnx1[t2]);        \
      anh1[t2] = MFMA16(Ahh1[4 + t2], (h1in), bnh1[t2]);        \
    }                                                           \
  }

__global__ __launch_bounds__(64, 1) void gru_fused(
    const float* __restrict__ x,
    const float* __restrict__ wih0, const float* __restrict__ whh0,
    const float* __restrict__ bih0, const float* __restrict__ bhh0,
    const float* __restrict__ wih1, const float* __restrict__ whh1,
    const float* __restrict__ bih1, const float* __restrict__ bhh1,
    const float* __restrict__ wcls, const float* __restrict__ bcls,
    float* __restrict__ out) {
  const int lane = threadIdx.x & 63;
  const int q = lane >> 4;
  const int c = lane & 15;
  const int b = blockIdx.x * 16 + c;

  // issue first x loads ASAP so they overlap weight-fragment setup
  const float* px = x + ((size_t)b * T_) * 64 + 8 * q;
  XRaw q0 = xload(px);          // x(0)
  XRaw qA = xload(px + 64);     // x(1)
  XRaw qB = xload(px + 128);    // x(2)

  // ---- weight fragments (permuted + prescaled), held in registers ----
  short8 Aih0[6][2], Ahh0[6], Aih1[6], Ahh1[6];
#pragma unroll
  for (int mt = 0; mt < 6; mt++) {
    Aih0[mt][0] = load_wfrag(wih0, 64, mt, 0, q, c);
    Aih0[mt][1] = load_wfrag(wih0, 64, mt, 1, q, c);
    Ahh0[mt] = load_wfrag(whh0, 32, mt, 0, q, c);
    Aih1[mt] = load_wfrag(wih1, 32, mt, 0, q, c);
    Ahh1[mt] = load_wfrag(whh1, 32, mt, 0, q, c);
  }
  floatx4 brz0[4], brz1[4], bnx0[2], bnh0[2], bnx1[2], bnh1[2];
#pragma unroll
  for (int tau = 0; tau < 4; tau++) {
    brz0[tau] = bias_rz(bih0, bhh0, tau, q);
    brz1[tau] = bias_rz(bih1, bhh1, tau, q);
  }
#pragma unroll
  for (int t2 = 0; t2 < 2; t2++) {
    bnx0[t2] = bias_n(bih0, t2, q);
    bnh0[t2] = bias_n(bhh0, t2, q);
    bnx1[t2] = bias_n(bih1, t2, q);
    bnh1[t2] = bias_n(bhh1, t2, q);
  }

  // ---- state ----
  float h0[8], h1[8];
  short8 h0f_p, h0f_n, h1f;
#pragma unroll
  for (int j = 0; j < 8; j++) {
    h0[j] = 0.f;
    h1[j] = 0.f;
    h0f_p[j] = 0;
    h0f_n[j] = 0;
    h1f[j] = 0;
  }

  floatx4 arz0[4], anx0[2], anh0[2];
  floatx4 arz1[4], anx1[2], anh1[2];
  short8 xfA0, xfA1, xfB0, xfB1;

  // ---- prologue: L0(0) only (layer 1 runs one step behind) ----
  {
    short8 x00, x01;
    xconv(q0, x00, x01);
    LAYER0_MFMAS(x00, x01, h0f_p);
    gru_update(arz0, anx0, anh0, h0, &h0f_p);  // h0f_p = h0f(0)
    xconv(qA, xfA0, xfA1);                     // x(1) frags
  }

  // ---- main loop: iteration computes L0(i) || L1(i-1); unrolled by 2 so the
  //      raw-x queue rotates by renaming (qA/qB), no copies forcing waits ----
  int i = 1;
  for (; i + 1 < T_; i += 2) {
    // -- sub-step A: t = i. Uses xfA=x(i), h0f_p=h0f(i-1). --
    qA = xload(px + (size_t)(i + 2) * 64);  // i+2 <= T_-1 always here
    LAYER0_MFMAS(xfA0, xfA1, h0f_p);
    LAYER1_MFMAS(h0f_p, h1f);
    gru_update(arz0, anx0, anh0, h0, &h0f_n);  // h0f(i)
    gru_update(arz1, anx1, anh1, h1, &h1f);    // h1f(i-1)
    xconv(qB, xfB0, xfB1);                     // x(i+1) frags

    // -- sub-step B: t = i+1. Uses xfB, h0f_n=h0f(i). --
    {
      const int t3 = (i + 3 < T_) ? (i + 3) : (T_ - 1);
      qB = xload(px + (size_t)t3 * 64);
    }
    LAYER0_MFMAS(xfB0, xfB1, h0f_n);
    LAYER1_MFMAS(h0f_n, h1f);
    gru_update(arz0, anx0, anh0, h0, &h0f_p);  // h0f(i+1)
    gru_update(arz1, anx1, anh1, h1, &h1f);    // h1f(i)
    xconv(qA, xfA0, xfA1);                     // x(i+2) frags
  }

  // ---- leftover step t = T_-1 (odd count): L0(T-1) || L1(T-2) ----
  LAYER0_MFMAS(xfA0, xfA1, h0f_p);
  LAYER1_MFMAS(h0f_p, h1f);
  gru_update(arz0, anx0, anh0, h0, &h0f_n);  // h0 final state
  gru_update(arz1, anx1, anh1, h1, &h1f);    // h1f(T-2)

  // ---- epilogue: L1(T-1) ----
  LAYER1_MFMAS(h0f_n, h1f);
  gru_update(arz1, anx1, anh1, h1, &h1f);    // h1 final state

  // ---- outputs (fp32): y[2048], hidden[2][2048][32], h logical k=8q+j ----
  float* oh0 = out + 2048 + (size_t)b * 32 + 8 * q;
  float* oh1 = oh0 + 65536;
  *(float4*)oh0 = make_float4(h0[0], h0[1], h0[2], h0[3]);
  *(float4*)(oh0 + 4) = make_float4(h0[4], h0[5], h0[6], h0[7]);
  *(float4*)oh1 = make_float4(h1[0], h1[1], h1[2], h1[3]);
  *(float4*)(oh1 + 4) = make_float4(h1[4], h1[5], h1[6], h1[7]);

  float wc[8];
#pragma unroll
  for (int j = 0; j < 8; j++) wc[j] = wcls[8 * q + j];
  float acc = 0.f;
#pragma unroll
  for (int j = 0; j < 8; j++) acc = fmaf(h1[j], wc[j], acc);
  acc += __shfl_xor(acc, 16, 64);
  acc += __shfl_xor(acc, 32, 64);
  if (q == 0) {
    float pre = acc + bcls[0];
    out[b] = __builtin_amdgcn_rcpf(1.0f + __builtin_amdgcn_exp2f(NLOG2E * pre));
  }
}

extern "C" void kernel_launch(void* const* d_in, const int* in_sizes, int n_in,
                              void* d_out, int out_size, void* d_ws, size_t ws_size,
                              hipStream_t stream) {
  const float* x    = (const float*)d_in[0];
  const float* wih0 = (const float*)d_in[1];
  const float* whh0 = (const float*)d_in[2];
  const float* bih0 = (const float*)d_in[3];
  const float* bhh0 = (const float*)d_in[4];
  const float* wih1 = (const float*)d_in[5];
  const float* whh1 = (const float*)d_in[6];
  const float* bih1 = (const float*)d_in[7];
  const float* bhh1 = (const float*)d_in[8];
  const float* wcls = (const float*)d_in[9];
  const float* bcls = (const float*)d_in[10];
  float* out = (float*)d_out;

  gru_fused<<<dim3(B_ / 16), dim3(64), 0, stream>>>(
      x, wih0, whh0, bih0, bhh0, wih1, whh1, bih1, bhh1, wcls, bcls, out);
}

// Round 2
// 1687.180 us; speedup vs baseline: 1.5972x; 1.0034x over previous
//
// Fused 2-layer GRU + classifier head, MI355X gfx950.
// B=2048, T=1024, D=64, H=32. Inputs/outputs FLOAT32; bf16 MFMA internally.
//
// Design (round 4):
//  - 128 blocks x 128 threads (2 waves). WAVE-SPECIALIZED LAYER SPLIT:
//    wave 0 runs layer 0 for 16 batch rows across all 1024 steps; wave 1 runs
//    layer 1 one step behind, consuming h0f through a 2-slot LDS buffer with
//    ONE s_barrier per step. Rationale: round-3 counters showed the single
//    wave per SIMD issuing VALU ~70% of cycles, dominated by 96 trans ops/step
//    (3 exp2 + 3 rcp x 16 elem x 2 layers) at ~16 cy each -> trans-issue-bound.
//    Splitting layers across waves halves each wave's trans load (48/step).
//  - Slot protocol: wave0 writes h0f(i) -> slot[i&1], lgkmcnt(0), s_barrier(i).
//    wave1 after s_barrier(j) reads slot[j&1] = h0f(j), computes L1(j).
//    Same-slot write (bar i-1, bar i) vs read (bar i-2..) always barrier-
//    separated. Raw s_barrier + lgkmcnt-only wait: no vmcnt drain, so wave0's
//    2-step-ahead x prefetch stays in flight across barriers.
//  - wave1 MFMA chain reordered (Ahh1*h1f first, then +Aih1*h0f) so the
//    per-step ds_read latency hides under the h1-only MFMAs.
//  - bf16 packing via __float2bfloat16 pairs -> v_cvt_pk_bf16_f32.
//  - MFMA: D[gate][batch] = W' @ h^T (M=96 gates as 6 16-row tiles, N=16
//    batch, K=32/64), mfma_f32_16x16x32_bf16, fp32 accumulate.
//  - rho row-permutation rho(16*tau+4*q+r)=8q+4*tau+r: z/n tiles' C/D
//    registers land exactly in B-operand layout for the next step's hidden
//    matvec -> zero cross-lane movement per step.
//  - Pre-scaling: r,z rows * -log2(e) -> sigmoid = rcp(1+exp2(acc));
//                 n rows  * 2*log2(e) -> tanh    = 1-2*rcp(1+exp2(acc)).
//    fp32 biases folded into MFMA C-init fragments (free).

#include <hip/hip_runtime.h>
#include <hip/hip_bf16.h>

#define B_ 2048
#define T_ 1024

typedef short short8 __attribute__((ext_vector_type(8)));
typedef float floatx4 __attribute__((ext_vector_type(4)));

#define MFMA16(a, b, c) __builtin_amdgcn_mfma_f32_16x16x32_bf16((a), (b), (c), 0, 0, 0)
#define NLOG2E -1.4426950408889634f
#define TWOLOG2E 2.8853900817779268f

// init-time scalar fp32->bf16 RNE (weight fragments only)
__device__ __forceinline__ unsigned short f2bf(float f) {
  union { float f; unsigned int i; } v;
  v.f = f;
  unsigned int r = v.i + 0x7fffu + ((v.i >> 16) & 1u);  // RNE
  return (unsigned short)(r >> 16);
}

// hot-loop pack: compiler fuses the two scalar casts into v_cvt_pk_bf16_f32
__device__ __forceinline__ unsigned int pack2(float lo, float hi) {
  __hip_bfloat162 h2;
  h2.x = __float2bfloat16(lo);
  h2.y = __float2bfloat16(hi);
  union { __hip_bfloat162 h; unsigned int u; } v;
  v.h = h2;
  return v.u;
}

// position within a 32-row gate block -> logical (torch) row index
__device__ __forceinline__ int rho32(int pb) {
  return 8 * ((pb >> 2) & 3) + 4 * (pb >> 4) + (pb & 3);
}

// A-operand fragment of permuted+prescaled weight matrix W' (96 x K), fp32 src.
__device__ __forceinline__ short8 load_wfrag(const float* W, int K,
                                             int mt, int kt, int q, int c) {
  int p = 16 * mt + c;
  int blk = p >> 5;
  int pb = p & 31;
  int tr = 32 * blk + rho32(pb);
  float s = (blk < 2) ? NLOG2E : TWOLOG2E;
  const float* src = W + tr * K + 32 * kt + 8 * q;
  short8 out;
#pragma unroll
  for (int j = 0; j < 8; j++) out[j] = (short)f2bf(src[j] * s);
  return out;
}

// C-init fragment for r,z tiles (tau 0..3): -log2e*(b_ih+b_hh), permuted rows
__device__ __forceinline__ floatx4 bias_rz(const float* bih, const float* bhh,
                                           int tau, int q) {
  floatx4 f;
#pragma unroll
  for (int r = 0; r < 4; r++) {
    int p = 16 * tau + 4 * q + r;
    int idx = 32 * (p >> 5) + rho32(p & 31);
    f[r] = NLOG2E * (bih[idx] + bhh[idx]);
  }
  return f;
}
// C-init fragment for n tiles: 2*log2e * bias[64 + rho]
__device__ __forceinline__ floatx4 bias_n(const float* bias, int tau2, int q) {
  floatx4 f;
#pragma unroll
  for (int r = 0; r < 4; r++) {
    int pb = 16 * tau2 + 4 * q + r;
    f[r] = TWOLOG2E * bias[64 + rho32(pb)];
  }
  return f;
}

// raw (fp32) x for one step: lane(q,c) holds x[b][t][8q..8q+7] and [32+8q..+7]
struct XRaw { float4 r0, r1, r2, r3; };
__device__ __forceinline__ XRaw xload(const float* p) {
  XRaw r;
  r.r0 = *(const float4*)p;
  r.r1 = *(const float4*)(p + 4);
  r.r2 = *(const float4*)(p + 32);
  r.r3 = *(const float4*)(p + 36);
  return r;
}
__device__ __forceinline__ void xconv(const XRaw& r, short8& f0, short8& f1) {
  union { short8 s8; unsigned int u[4]; } P;
  P.u[0] = pack2(r.r0.x, r.r0.y);
  P.u[1] = pack2(r.r0.z, r.r0.w);
  P.u[2] = pack2(r.r1.x, r.r1.y);
  P.u[3] = pack2(r.r1.z, r.r1.w);
  f0 = P.s8;
  P.u[0] = pack2(r.r2.x, r.r2.y);
  P.u[1] = pack2(r.r2.z, r.r2.w);
  P.u[2] = pack2(r.r3.x, r.r3.y);
  P.u[3] = pack2(r.r3.z, r.r3.w);
  f1 = P.s8;
}

// GRU gate elementwise + h update + bf16 repack into B-operand fragment.
__device__ __forceinline__ void gru_update(const floatx4* arz, const floatx4* anx,
                                           const floatx4* anh, float* h,
                                           short8* hf) {
#pragma unroll
  for (int t2 = 0; t2 < 2; t2++) {
#pragma unroll
    for (int r = 0; r < 4; r++) {
      float rr = __builtin_amdgcn_rcpf(1.0f + __builtin_amdgcn_exp2f(arz[t2][r]));
      float zz = __builtin_amdgcn_rcpf(1.0f + __builtin_amdgcn_exp2f(arz[2 + t2][r]));
      float u = fmaf(rr, anh[t2][r], anx[t2][r]);
      float nn = fmaf(-2.0f, __builtin_amdgcn_rcpf(1.0f + __builtin_amdgcn_exp2f(u)), 1.0f);
      int j = 4 * t2 + r;
      h[j] = fmaf(zz, h[j] - nn, nn);  // (1-z)*n + z*h
    }
  }
  union { short8 s8; unsigned int u[4]; } P;
#pragma unroll
  for (int k2 = 0; k2 < 4; k2++) P.u[k2] = pack2(h[2 * k2], h[2 * k2 + 1]);
  *hf = P.s8;
}

// All 18 layer-0 MFMAs for one step (xa/xb = x frags, h0in = h0f fragment).
#define LAYER0_MFMAS(xa, xb, h0in)                              \
  {                                                             \
    _Pragma("unroll") for (int tau = 0; tau < 4; tau++) {       \
      floatx4 a_ = MFMA16(Aih0[tau][0], (xa), brz0[tau]);       \
      a_ = MFMA16(Aih0[tau][1], (xb), a_);                      \
      arz[tau] = MFMA16(Ahh0[tau], (h0in), a_);                 \
    }                                                           \
    _Pragma("unroll") for (int t2 = 0; t2 < 2; t2++) {          \
      floatx4 a_ = MFMA16(Aih0[4 + t2][0], (xa), bnx0[t2]);     \
      anx[t2] = MFMA16(Aih0[4 + t2][1], (xb), a_);              \
      anh[t2] = MFMA16(Ahh0[4 + t2], (h0in), bnh0[t2]);         \
    }                                                           \
  }

// All 12 layer-1 MFMAs for one step. h1f-dependent MFMAs FIRST so the
// ds_read of h0in can complete underneath them.
#define LAYER1_MFMAS(h0in, h1in)                                \
  {                                                             \
    floatx4 t_[4];                                              \
    _Pragma("unroll") for (int tau = 0; tau < 4; tau++)         \
      t_[tau] = MFMA16(Ahh1[tau], (h1in), brz1[tau]);           \
    _Pragma("unroll") for (int t2 = 0; t2 < 2; t2++)            \
      anh[t2] = MFMA16(Ahh1[4 + t2], (h1in), bnh1[t2]);         \
    _Pragma("unroll") for (int tau = 0; tau < 4; tau++)         \
      arz[tau] = MFMA16(Aih1[tau], (h0in), t_[tau]);            \
    _Pragma("unroll") for (int t2 = 0; t2 < 2; t2++)            \
      anx[t2] = MFMA16(Aih1[4 + t2], (h0in), bnx1[t2]);         \
  }

#define LGKM0_BARRIER()                                   \
  asm volatile("s_waitcnt lgkmcnt(0)" ::: "memory");      \
  __builtin_amdgcn_s_barrier()

__global__ __launch_bounds__(128, 1) void gru_fused(
    const float* __restrict__ x,
    const float* __restrict__ wih0, const float* __restrict__ whh0,
    const float* __restrict__ bih0, const float* __restrict__ bhh0,
    const float* __restrict__ wih1, const float* __restrict__ whh1,
    const float* __restrict__ bih1, const float* __restrict__ bhh1,
    const float* __restrict__ wcls, const float* __restrict__ bcls,
    float* __restrict__ out) {
  const int lane = threadIdx.x & 63;
  const int w = threadIdx.x >> 6;
  const int q = lane >> 4;
  const int c = lane & 15;
  const int b = blockIdx.x * 16 + c;

  __shared__ short8 hslot[2][64];  // 2 KB: h0f double buffer

  floatx4 arz[4], anx[2], anh[2];

  if (w == 0) {
    // ================= WAVE 0: layer 0 =================
    const float* px = x + ((size_t)b * T_) * 64 + 8 * q;
    XRaw q0 = xload(px);          // x(0)
    XRaw qA = xload(px + 64);     // x(1)
    XRaw qB = xload(px + 128);    // x(2)

    short8 Aih0[6][2], Ahh0[6];
#pragma unroll
    for (int mt = 0; mt < 6; mt++) {
      Aih0[mt][0] = load_wfrag(wih0, 64, mt, 0, q, c);
      Aih0[mt][1] = load_wfrag(wih0, 64, mt, 1, q, c);
      Ahh0[mt] = load_wfrag(whh0, 32, mt, 0, q, c);
    }
    floatx4 brz0[4], bnx0[2], bnh0[2];
#pragma unroll
    for (int tau = 0; tau < 4; tau++) brz0[tau] = bias_rz(bih0, bhh0, tau, q);
#pragma unroll
    for (int t2 = 0; t2 < 2; t2++) {
      bnx0[t2] = bias_n(bih0, t2, q);
      bnh0[t2] = bias_n(bhh0, t2, q);
    }

    float h0[8];
    short8 h0f;
#pragma unroll
    for (int j = 0; j < 8; j++) { h0[j] = 0.f; h0f[j] = 0; }

    short8 xfA0, xfA1, xfB0, xfB1;

    // ---- step 0 ----
    {
      short8 x00, x01;
      xconv(q0, x00, x01);
      LAYER0_MFMAS(x00, x01, h0f);
      gru_update(arz, anx, anh, h0, &h0f);  // h0f(0)
      hslot[0][lane] = h0f;
      LGKM0_BARRIER();                      // bar 0
      xconv(qA, xfA0, xfA1);                // x(1) frags
    }

    // ---- steps 1..1022, unrolled by 2 (i odd) ----
    for (int i = 1; i + 1 < T_; i += 2) {
      // step i (odd -> slot 1), uses xfA = x(i)
      qA = xload(px + (size_t)(i + 2) * 64);  // i+2 <= T_-1 here
      LAYER0_MFMAS(xfA0, xfA1, h0f);
      gru_update(arz, anx, anh, h0, &h0f);    // h0f(i)
      hslot[1][lane] = h0f;
      LGKM0_BARRIER();                        // bar i
      xconv(qB, xfB0, xfB1);                  // x(i+1) frags

      // step i+1 (even -> slot 0), uses xfB = x(i+1)
      {
        const int t3 = (i + 3 < T_) ? (i + 3) : (T_ - 1);
        qB = xload(px + (size_t)t3 * 64);
      }
      LAYER0_MFMAS(xfB0, xfB1, h0f);
      gru_update(arz, anx, anh, h0, &h0f);    // h0f(i+1)
      hslot[0][lane] = h0f;
      LGKM0_BARRIER();                        // bar i+1
      xconv(qA, xfA0, xfA1);                  // x(i+2) frags
    }

    // ---- step 1023 (odd -> slot 1) ----
    LAYER0_MFMAS(xfA0, xfA1, h0f);
    gru_update(arz, anx, anh, h0, &h0f);      // h0 final
    hslot[1][lane] = h0f;
    LGKM0_BARRIER();                          // bar 1023

    // outputs: hidden[0]
    float* oh0 = out + 2048 + (size_t)b * 32 + 8 * q;
    *(float4*)oh0 = make_float4(h0[0], h0[1], h0[2], h0[3]);
    *(float4*)(oh0 + 4) = make_float4(h0[4], h0[5], h0[6], h0[7]);
  } else {
    // ================= WAVE 1: layer 1 =================
    short8 Aih1[6], Ahh1[6];
#pragma unroll
    for (int mt = 0; mt < 6; mt++) {
      Aih1[mt] = load_wfrag(wih1, 32, mt, 0, q, c);
      Ahh1[mt] = load_wfrag(whh1, 32, mt, 0, q, c);
    }
    floatx4 brz1[4], bnx1[2], bnh1[2];
#pragma unroll
    for (int tau = 0; tau < 4; tau++) brz1[tau] = bias_rz(bih1, bhh1, tau, q);
#pragma unroll
    for (int t2 = 0; t2 < 2; t2++) {
      bnx1[t2] = bias_n(bih1, t2, q);
      bnh1[t2] = bias_n(bhh1, t2, q);
    }
    float wc[8];
#pragma unroll
    for (int j = 0; j < 8; j++) wc[j] = wcls[8 * q + j];

    float h1[8];
    short8 h1f;
#pragma unroll
    for (int j = 0; j < 8; j++) { h1[j] = 0.f; h1f[j] = 0; }

    __builtin_amdgcn_s_barrier();  // bar 0: h0f(0) in slot 0

    // ---- steps j = 0..1021, unrolled by 2 (j even) ----
    for (int j = 0; j < T_ - 3; j += 2) {
      // step j (even -> slot 0)
      asm volatile("" ::: "memory");
      short8 h0in = hslot[0][lane];
      LAYER1_MFMAS(h0in, h1f);
      gru_update(arz, anx, anh, h1, &h1f);   // h1f(j)
      __builtin_amdgcn_s_barrier();          // bar j+1

      // step j+1 (odd -> slot 1)
      asm volatile("" ::: "memory");
      short8 h0in2 = hslot[1][lane];
      LAYER1_MFMAS(h0in2, h1f);
      gru_update(arz, anx, anh, h1, &h1f);   // h1f(j+1)
      __builtin_amdgcn_s_barrier();          // bar j+2
    }

    // ---- step 1022 (even -> slot 0) ----
    {
      asm volatile("" ::: "memory");
      short8 h0in = hslot[0][lane];
      LAYER1_MFMAS(h0in, h1f);
      gru_update(arz, anx, anh, h1, &h1f);
      __builtin_amdgcn_s_barrier();          // bar 1023
    }
    // ---- step 1023 (odd -> slot 1), no trailing barrier ----
    {
      asm volatile("" ::: "memory");
      short8 h0in = hslot[1][lane];
      LAYER1_MFMAS(h0in, h1f);
      gru_update(arz, anx, anh, h1, &h1f);   // h1 final
    }

    // outputs: hidden[1] + classifier
    float* oh1 = out + 2048 + 65536 + (size_t)b * 32 + 8 * q;
    *(float4*)oh1 = make_float4(h1[0], h1[1], h1[2], h1[3]);
    *(float4*)(oh1 + 4) = make_float4(h1[4], h1[5], h1[6], h1[7]);

    float acc = 0.f;
#pragma unroll
    for (int j = 0; j < 8; j++) acc = fmaf(h1[j], wc[j], acc);
    acc += __shfl_xor(acc, 16, 64);
    acc += __shfl_xor(acc, 32, 64);
    if (q == 0) {
      float pre = acc + bcls[0];
      out[b] = __builtin_amdgcn_rcpf(1.0f + __builtin_amdgcn_exp2f(NLOG2E * pre));
    }
  }
}

extern "C" void kernel_launch(void* const* d_in, const int* in_sizes, int n_in,
                              void* d_out, int out_size, void* d_ws, size_t ws_size,
                              hipStream_t stream) {
  const float* x    = (const float*)d_in[0];
  const float* wih0 = (const float*)d_in[1];
  const float* whh0 = (const float*)d_in[2];
  const float* bih0 = (const float*)d_in[3];
  const float* bhh0 = (const float*)d_in[4];
  const float* wih1 = (const float*)d_in[5];
  const float* whh1 = (const float*)d_in[6];
  const float* bih1 = (const float*)d_in[7];
  const float* bhh1 = (const float*)d_in[8];
  const float* wcls = (const float*)d_in[9];
  const float* bcls = (const float*)d_in[10];
  float* out = (float*)d_out;

  gru_fused<<<dim3(B_ / 16), dim3(128), 0, stream>>>(
      x, wih0, whh0, bih0, bhh0, wih1, whh1, bih1, bhh1, wcls, bcls, out);
}